// Round 10
// baseline (37824.698 us; speedup 1.0000x reference)
//
#include <hip/hip_runtime.h>
#include <stdint.h>

#define STEPS 100

// ---------------------------------------------------------------------------
// Threefry2x32 (JAX-exact, 20 rounds)
// ---------------------------------------------------------------------------
__device__ __forceinline__ uint32_t rotl32(uint32_t v, int r) {
  return (v << r) | (v >> (32 - r));
}

__device__ __forceinline__ void tf2x32(uint32_t k0, uint32_t k1,
                                       uint32_t x0, uint32_t x1,
                                       uint32_t& o0, uint32_t& o1) {
  uint32_t ks2 = k0 ^ k1 ^ 0x1BD11BDAu;
  x0 += k0; x1 += k1;
#define RND(r) { x0 += x1; x1 = rotl32(x1, (r)); x1 ^= x0; }
  RND(13) RND(15) RND(26) RND(6)
  x0 += k1;  x1 += ks2 + 1u;
  RND(17) RND(29) RND(16) RND(24)
  x0 += ks2; x1 += k0 + 2u;
  RND(13) RND(15) RND(26) RND(6)
  x0 += k0;  x1 += k1 + 3u;
  RND(17) RND(29) RND(16) RND(24)
  x0 += k1;  x1 += ks2 + 4u;
  RND(13) RND(15) RND(26) RND(6)
  x0 += ks2; x1 += k0 + 5u;
#undef RND
  o0 = x0; o1 = x1;
}

__global__ void keys_k(uint32_t* __restrict__ kb) {
  int i = threadIdx.x;
  if (i < STEPS) {
    uint32_t a, b;
    tf2x32(0u, 42u, 0u, (uint32_t)i, a, b);
    kb[2 * i] = a;
    kb[2 * i + 1] = b;
  }
}

__global__ void wt_k(const float* __restrict__ w2, float* __restrict__ wT) {
  int i = blockIdx.x * blockDim.x + threadIdx.x;
  if (i >= 25000) return;
  int oc = i / 500, q = i % 500;
  wT[q * 50 + oc] = w2[i];
}

// ---------------------------------------------------------------------------
// PERSISTENT per-sample kernel v2: one 512-thread block = one sample, all
// 100 steps. ALL membrane state in REGISTERS (thread-private by fixed
// mapping); LDS only for spike hand-offs. Weight reads stay scalar
// (oh = t>>8 is wave-uniform). sp2 spikes packed 4-per-dword to global
// layout [s][613][512] dwords for fc0f. Summation chains verbatim R8 ->
// bitwise identical output.
// ---------------------------------------------------------------------------
__global__ __launch_bounds__(512) void step_all_k(
    const float* __restrict__ x, const float* __restrict__ w1,
    const float* __restrict__ wT, const uint32_t* __restrict__ kb,
    uint32_t* __restrict__ sp2g) {
  __shared__ float  xh_l[784];        // |x|/2 per pixel
  __shared__ int8_t xs_l[784];        // sign(x)
  __shared__ int8_t pois_l[784];
  __shared__ int8_t sp1_l[20 * 196];
  __shared__ int8_t s2_l[50 * 196];

  const int b = blockIdx.x;
  const int t = threadIdx.x;
  const int lq = t & 255;             // pixel/quad index (active if < 196)
  const int oh = t >> 8;              // oc-half, wave-uniform
  const bool act = lq < 196;
  const int qy = lq / 14, qx = lq % 14;

  // preload per-sample input transform (reused all 100 steps)
  for (int p = t; p < 784; p += 512) {
    float xv = x[b * 784 + p];
    xh_l[p] = fabsf(xv) * 0.5f;
    xs_l[p] = (xv > 0.f) ? (int8_t)1 : ((xv < 0.f) ? (int8_t)-1 : (int8_t)0);
  }

  // thread-private membrane state (registers)
  float m1r[4][10], m1sr[10], m2r[25], m2sA[4], m2sB[4];
#pragma unroll
  for (int i = 0; i < 10; ++i) {
    m1sr[i] = 0.f;
#pragma unroll
    for (int tt = 0; tt < 4; ++tt) m1r[tt][i] = 0.f;
  }
#pragma unroll
  for (int i = 0; i < 25; ++i) m2r[i] = 0.f;
#pragma unroll
  for (int i = 0; i < 4; ++i) { m2sA[i] = 0.f; m2sB[i] = 0.f; }

  __syncthreads();

  for (int s = 0; s < STEPS; ++s) {
    // ---- P0: poisson spikes ----
    {
      uint32_t k0 = kb[2 * s], k1 = kb[2 * s + 1];
      for (int p = t; p < 784; p += 512) {
        uint32_t o0, o1;
        tf2x32(k0, k1, 0u, (uint32_t)(b * 784 + p), o0, o1);
        float r = __uint_as_float(((o0 ^ o1) >> 9) | 0x3F800000u) - 1.0f;
        pois_l[p] = (xh_l[p] > r) ? xs_l[p] : (int8_t)0;
      }
    }
    __syncthreads();

    // ---- P1: conv1 (10 oc of this half) + fire + pool1 + fire ----
    if (act) {
      float acc[4][10];
#pragma unroll
      for (int tt = 0; tt < 4; ++tt)
#pragma unroll
        for (int i = 0; i < 10; ++i) acc[tt][i] = 0.f;
#pragma unroll
      for (int tt = 0; tt < 4; ++tt) {
        int y = 2 * qy + (tt >> 1);
        int xx = 2 * qx + (tt & 1);
#pragma unroll
        for (int ky = 0; ky < 5; ++ky) {
          int iy = y + ky - 2;
          if (iy < 0 || iy >= 28) continue;
#pragma unroll
          for (int kx = 0; kx < 5; ++kx) {
            int ix = xx + kx - 2;
            if (ix < 0 || ix >= 28) continue;
            float v = (float)pois_l[iy * 28 + ix];
#pragma unroll
            for (int i = 0; i < 10; ++i)
              acc[tt][i] += w1[(oh * 10 + i) * 25 + ky * 5 + kx] * v;
          }
        }
      }
#pragma unroll
      for (int i = 0; i < 10; ++i) {
        float s4[4];
#pragma unroll
        for (int tt = 0; tt < 4; ++tt) {
          float m = m1r[tt][i] + acc[tt][i];
          float sp = 0.f;
          if (m > 1.0f) { sp = 1.f; m = 0.f; }
          m1r[tt][i] = m;
          s4[tt] = sp;
        }
        float a = 0.25f * (((s4[0] + s4[1]) + s4[2]) + s4[3]);
        float mm = m1sr[i] + a;
        int8_t spp = 0;
        if (mm > 0.75f) { spp = 1; mm = 0.f; }
        m1sr[i] = mm;
        sp1_l[(oh * 10 + i) * 196 + lq] = spp;
      }
    }
    __syncthreads();

    // ---- P2: conv2 (25 oc of this half) + fire ----
    if (act) {
      float acc[25];
#pragma unroll
      for (int i = 0; i < 25; ++i) acc[i] = 0.f;
      for (int ic = 0; ic < 20; ++ic) {
#pragma unroll
        for (int ky = 0; ky < 5; ++ky) {
          int iy = qy + ky - 2;
          if (iy < 0 || iy >= 14) continue;
#pragma unroll
          for (int kx = 0; kx < 5; ++kx) {
            int ix = qx + kx - 2;
            if (ix < 0 || ix >= 14) continue;
            float v = (float)sp1_l[ic * 196 + iy * 14 + ix];
            const float* wrow = wT + (ic * 25 + ky * 5 + kx) * 50 + oh * 25;
#pragma unroll
            for (int i = 0; i < 25; ++i) acc[i] += wrow[i] * v;
          }
        }
      }
#pragma unroll
      for (int i = 0; i < 25; ++i) {
        float m = m2r[i] + acc[i];
        int8_t sp = 0;
        if (m > 1.0f) { sp = 1; m = 0.f; }
        m2r[i] = m;
        s2_l[(oh * 25 + i) * 196 + lq] = sp;
      }
    }
    __syncthreads();

    // ---- P3: pool2 + fire + packed dword store [s][613][512] ----
    {
      // quad A: qd = t (e = 4t+i <= 2047 < 2450, always valid)
      uint32_t pack = 0;
#pragma unroll
      for (int i = 0; i < 4; ++i) {
        int e = 4 * t + i;
        int oc = e / 49, qq = e % 49;
        int yo = qq / 7, xo = qq % 7;
        int ib = oc * 196 + 2 * yo * 14 + 2 * xo;
        float a = 0.25f * ((((float)s2_l[ib] + (float)s2_l[ib + 1]) +
                            (float)s2_l[ib + 14]) + (float)s2_l[ib + 15]);
        float m = m2sA[i] + a;
        if (m > 0.75f) { pack |= (1u << (8 * i)); m = 0.f; }
        m2sA[i] = m;
      }
      sp2g[(size_t)(s * 613 + t) * 512 + b] = pack;

      if (t < 101) {                  // quad B: qd = t+512 (<= 612)
        int qd = t + 512;
        uint32_t pack2 = 0;
#pragma unroll
        for (int i = 0; i < 4; ++i) {
          int e = 4 * qd + i;
          if (e < 2450) {
            int oc = e / 49, qq = e % 49;
            int yo = qq / 7, xo = qq % 7;
            int ib = oc * 196 + 2 * yo * 14 + 2 * xo;
            float a = 0.25f * ((((float)s2_l[ib] + (float)s2_l[ib + 1]) +
                                (float)s2_l[ib + 14]) + (float)s2_l[ib + 15]);
            float m = m2sB[i] + a;
            if (m > 0.75f) { pack2 |= (1u << (8 * i)); m = 0.f; }
            m2sB[i] = m;
          }
        }
        sp2g[(size_t)(s * 613 + qd) * 512 + b] = pack2;
      }
    }
    __syncthreads();
  }
}

// ---------------------------------------------------------------------------
// fc0 over ALL steps. Thread = (n,b); mf0/Tf0 in registers across s.
// Packed u32 loads (4 spikes each), k ascending -> bit-identical.
// ---------------------------------------------------------------------------
__global__ __launch_bounds__(256) void fc0f_k(
    const uint32_t* __restrict__ sp2g, const float* __restrict__ wf0,
    float* __restrict__ Tf0g) {
  int n = blockIdx.x >> 1;                        // block-uniform
  int b = ((blockIdx.x & 1) << 8) + threadIdx.x;  // 0..511
  const float* w0 = wf0 + n * 2450;               // scalar, K$-resident
  float m = 0.f, T = 0.f;
  for (int s = 0; s < STEPS; ++s) {
    const uint32_t* base = sp2g + (size_t)s * 613 * 512 + b;
    float acc = 0.f;
    for (int kq0 = 0; kq0 < 612; kq0 += 12) {     // 612 = 12*51
      uint32_t w[12];
#pragma unroll
      for (int u = 0; u < 12; ++u) w[u] = base[(kq0 + u) * 512];
#pragma unroll
      for (int u = 0; u < 12; ++u) {
        int k = (kq0 + u) * 4;
        acc += w0[k]     * (float)(w[u] & 0xffu);
        acc += w0[k + 1] * (float)((w[u] >> 8) & 0xffu);
        acc += w0[k + 2] * (float)((w[u] >> 16) & 0xffu);
        acc += w0[k + 3] * (float)(w[u] >> 24);
      }
    }
    uint32_t wl = base[612 * 512];                // k = 2448, 2449
    acc += w0[2448] * (float)(wl & 0xffu);
    acc += w0[2449] * (float)((wl >> 8) & 0xffu);
    m += acc;
    if (m > 1.0f) { T += 1.f; m = 0.f; }
  }
  Tf0g[n * 512 + b] = T;
}

// ---------------------------------------------------------------------------
// final: out[b][i] = (Tf0[.][b] . wf1[i][.]) / 1 / 100   (j ascending)
// ---------------------------------------------------------------------------
__global__ void fc1_k(const float* __restrict__ Tf0,
                      const float* __restrict__ wf1,
                      float* __restrict__ out) {
  int idx = blockIdx.x * blockDim.x + threadIdx.x;
  if (idx >= 5120) return;
  int b = idx / 10, i = idx % 10;
  float a = 0.f;
  for (int j = 0; j < 200; ++j) a += Tf0[j * 512 + b] * wf1[i * 200 + j];
  out[idx] = (a / 1.0f) / 100.0f;
}

// ---------------------------------------------------------------------------
// Fallback path (R8-proven), used only if ws_size is too small.
// ---------------------------------------------------------------------------
__global__ void pois_k(const float* __restrict__ x,
                       const uint32_t* __restrict__ kb, int step,
                       int8_t* __restrict__ pois) {
  int t = blockIdx.x * blockDim.x + threadIdx.x;
  if (t >= 401408) return;
  int p = t >> 9, b = t & 511;
  int j = b * 784 + p;
  uint32_t k0 = kb[2 * step], k1 = kb[2 * step + 1];
  uint32_t o0, o1;
  tf2x32(k0, k1, 0u, (uint32_t)j, o0, o1);
  uint32_t bits = o0 ^ o1;
  float r = __uint_as_float((bits >> 9) | 0x3F800000u) - 1.0f;
  float xv = x[j];
  int8_t sgn = (xv > 0.f) ? (int8_t)1 : ((xv < 0.f) ? (int8_t)-1 : (int8_t)0);
  pois[t] = (fabsf(xv) * 0.5f > r) ? sgn : (int8_t)0;
}

__global__ __launch_bounds__(256) void c1_k(
    const int8_t* __restrict__ pois, const float* __restrict__ w1,
    float* __restrict__ m1, float* __restrict__ m1s,
    uint8_t* __restrict__ sp1) {
  int q = blockIdx.x >> 1;
  int b = ((blockIdx.x & 1) << 8) + threadIdx.x;
  int qy = q / 14, qx = q % 14;
  float acc[4][20];
#pragma unroll
  for (int t = 0; t < 4; ++t)
#pragma unroll
    for (int oc = 0; oc < 20; ++oc) acc[t][oc] = 0.f;
#pragma unroll
  for (int t = 0; t < 4; ++t) {
    int y = 2 * qy + (t >> 1);
    int xx = 2 * qx + (t & 1);
#pragma unroll
    for (int ky = 0; ky < 5; ++ky) {
      int iy = y + ky - 2;
      if (iy < 0 || iy >= 28) continue;
#pragma unroll
      for (int kx = 0; kx < 5; ++kx) {
        int ix = xx + kx - 2;
        if (ix < 0 || ix >= 28) continue;
        float v = (float)pois[(iy * 28 + ix) * 512 + b];
#pragma unroll
        for (int oc = 0; oc < 20; ++oc)
          acc[t][oc] += w1[oc * 25 + ky * 5 + kx] * v;
      }
    }
  }
#pragma unroll
  for (int oc = 0; oc < 20; ++oc) {
    float s4[4];
#pragma unroll
    for (int t = 0; t < 4; ++t) {
      int y = 2 * qy + (t >> 1);
      int xx = 2 * qx + (t & 1);
      int idx = (oc * 784 + y * 28 + xx) * 512 + b;
      float m = m1[idx] + acc[t][oc];
      float sp = 0.f;
      if (m > 1.0f) { sp = 1.f; m = 0.f; }
      m1[idx] = m;
      s4[t] = sp;
    }
    float a = 0.25f * (((s4[0] + s4[1]) + s4[2]) + s4[3]);
    int pidx = (oc * 196 + q) * 512 + b;
    float mm = m1s[pidx] + a;
    uint8_t spp = 0;
    if (mm > 0.75f) { spp = 1; mm = 0.f; }
    m1s[pidx] = mm;
    sp1[pidx] = spp;
  }
}

__global__ __launch_bounds__(256) void c2_k(
    const uint8_t* __restrict__ sp1, const float* __restrict__ wT,
    float* __restrict__ m2, uint8_t* __restrict__ s2) {
  int p = blockIdx.x >> 1;
  int b = ((blockIdx.x & 1) << 8) + threadIdx.x;
  int y = p / 14, xx = p % 14;
  float acc[50];
#pragma unroll
  for (int oc = 0; oc < 50; ++oc) acc[oc] = 0.f;
  for (int ic = 0; ic < 20; ++ic) {
#pragma unroll
    for (int ky = 0; ky < 5; ++ky) {
      int iy = y + ky - 2;
      if (iy < 0 || iy >= 14) continue;
#pragma unroll
      for (int kx = 0; kx < 5; ++kx) {
        int ix = xx + kx - 2;
        if (ix < 0 || ix >= 14) continue;
        float v = (float)sp1[(ic * 196 + iy * 14 + ix) * 512 + b];
        const float* wrow = wT + (ic * 25 + ky * 5 + kx) * 50;
#pragma unroll
        for (int oc = 0; oc < 50; ++oc)
          acc[oc] += wrow[oc] * v;
      }
    }
  }
#pragma unroll
  for (int oc = 0; oc < 50; ++oc) {
    int idx = (oc * 196 + p) * 512 + b;
    float m = m2[idx] + acc[oc];
    uint8_t sp = 0;
    if (m > 1.0f) { sp = 1; m = 0.f; }
    m2[idx] = m;
    s2[idx] = sp;
  }
}

__global__ void p2_k(const uint8_t* __restrict__ s2, float* __restrict__ m2s,
                     uint8_t* __restrict__ sp2) {
  int t = blockIdx.x * blockDim.x + threadIdx.x;
  if (t >= 1254400) return;
  int b = t & 511;
  int r = t >> 9;
  int c = r / 49, qq = r % 49;
  int yo = qq / 7, xo = qq % 7;
  int ibase = (c * 196 + 2 * yo * 14 + 2 * xo) * 512 + b;
  float s00 = (float)s2[ibase];
  float s01 = (float)s2[ibase + 512];
  float s10 = (float)s2[ibase + 14 * 512];
  float s11 = (float)s2[ibase + 14 * 512 + 512];
  float a = 0.25f * (((s00 + s01) + s10) + s11);
  float m = m2s[t] + a;
  uint8_t sp = 0;
  if (m > 0.75f) { sp = 1; m = 0.f; }
  m2s[t] = m;
  sp2[t] = sp;
}

__global__ __launch_bounds__(256) void fc0_k(
    const uint8_t* __restrict__ sp2, const float* __restrict__ wf0,
    float* __restrict__ mf0, float* __restrict__ Tf0) {
  int n = blockIdx.x >> 1;
  int b = ((blockIdx.x & 1) << 8) + threadIdx.x;
  const float* w0 = wf0 + n * 2450;
  float acc = 0.f;
  for (int k0 = 0; k0 < 2450; k0 += 10) {
    float v[10];
#pragma unroll
    for (int u = 0; u < 10; ++u)
      v[u] = (float)sp2[(k0 + u) * 512 + b];
#pragma unroll
    for (int u = 0; u < 10; ++u)
      acc += w0[k0 + u] * v[u];
  }
  int idx = n * 512 + b;
  float m = mf0[idx] + acc;
  float sp = 0.f;
  if (m > 1.0f) { sp = 1.f; m = 0.f; }
  mf0[idx] = m;
  Tf0[idx] += sp;
}

// ---------------------------------------------------------------------------
extern "C" void kernel_launch(void* const* d_in, const int* in_sizes, int n_in,
                              void* d_out, int out_size, void* d_ws, size_t ws_size,
                              hipStream_t stream) {
  (void)in_sizes; (void)n_in; (void)out_size;
  const float* x   = (const float*)d_in[0];
  const float* w1  = (const float*)d_in[1];
  const float* w2  = (const float*)d_in[2];
  const float* wf0 = (const float*)d_in[3];
  const float* wf1 = (const float*)d_in[4];
  float* out = (float*)d_out;
  char* ws = (char*)d_ws;

  // ---- main-path workspace (bytes) ----
  const size_t tf0_b = 200ull * 512 * 4;          //    409,600
  const size_t wt_b  = 25000ull * 4;              //    100,000
  const size_t key_b = 1024;
  const size_t sp2_b = 100ull * 613 * 512 * 4;    // 125,542,400
  const size_t need = tf0_b + wt_b + key_b + sp2_b;

  if (ws_size >= need) {
    float*    Tf0g = (float*)ws;
    float*    wT   = (float*)(ws + tf0_b);
    uint32_t* kb   = (uint32_t*)(ws + tf0_b + wt_b);
    uint32_t* sp2g = (uint32_t*)(ws + tf0_b + wt_b + key_b);

    // no memset needed: every word read is written first
    keys_k<<<1, 128, 0, stream>>>(kb);
    wt_k<<<98, 256, 0, stream>>>(w2, wT);
    step_all_k<<<512, 512, 0, stream>>>(x, w1, wT, kb, sp2g);
    fc0f_k<<<400, 256, 0, stream>>>(sp2g, wf0, Tf0g);
    fc1_k<<<20, 256, 0, stream>>>(Tf0g, wf1, out);
    return;
  }

  // ---- fallback: R8-proven multi-kernel path ----
  float* m1   = (float*)ws;
  float* m1s  = m1   + 8028160;
  float* m2   = m1s  + 2007040;
  float* m2s  = m2   + 5017600;
  float* mf0  = m2s  + 1254400;
  float* Tf0  = mf0  + 102400;
  const size_t state_f = 8028160 + 2007040 + 5017600 + 1254400 + 102400 + 102400;
  float* wT   = Tf0  + 102400;
  uint32_t* keybuf = (uint32_t*)(wT + 25000);
  int8_t*  pois = (int8_t*)(keybuf + 256);
  uint8_t* sp1  = (uint8_t*)(pois + 401408);
  uint8_t* s2   = sp1 + 2007040;
  uint8_t* sp2  = s2  + 5017600;

  hipMemsetAsync(ws, 0, state_f * sizeof(float), stream);
  keys_k<<<1, 128, 0, stream>>>(keybuf);
  wt_k<<<98, 256, 0, stream>>>(w2, wT);
  for (int s = 0; s < STEPS; ++s) {
    pois_k<<<1568, 256, 0, stream>>>(x, keybuf, s, pois);
    c1_k<<<392, 256, 0, stream>>>(pois, w1, m1, m1s, sp1);
    c2_k<<<392, 256, 0, stream>>>(sp1, wT, m2, s2);
    p2_k<<<4900, 256, 0, stream>>>(s2, m2s, sp2);
    fc0_k<<<400, 256, 0, stream>>>(sp2, wf0, mf0, Tf0);
  }
  fc1_k<<<20, 256, 0, stream>>>(Tf0, wf1, out);
}

// Round 11
// 23082.224 us; speedup vs baseline: 1.6387x; 1.6387x over previous
//
#include <hip/hip_runtime.h>
#include <stdint.h>

#define STEPS 100

// ---------------------------------------------------------------------------
// Threefry2x32 (JAX-exact, 20 rounds)
// ---------------------------------------------------------------------------
__device__ __forceinline__ uint32_t rotl32(uint32_t v, int r) {
  return (v << r) | (v >> (32 - r));
}

__device__ __forceinline__ void tf2x32(uint32_t k0, uint32_t k1,
                                       uint32_t x0, uint32_t x1,
                                       uint32_t& o0, uint32_t& o1) {
  uint32_t ks2 = k0 ^ k1 ^ 0x1BD11BDAu;
  x0 += k0; x1 += k1;
#define RND(r) { x0 += x1; x1 = rotl32(x1, (r)); x1 ^= x0; }
  RND(13) RND(15) RND(26) RND(6)
  x0 += k1;  x1 += ks2 + 1u;
  RND(17) RND(29) RND(16) RND(24)
  x0 += ks2; x1 += k0 + 2u;
  RND(13) RND(15) RND(26) RND(6)
  x0 += k0;  x1 += k1 + 3u;
  RND(17) RND(29) RND(16) RND(24)
  x0 += k1;  x1 += ks2 + 4u;
  RND(13) RND(15) RND(26) RND(6)
  x0 += ks2; x1 += k0 + 5u;
#undef RND
  o0 = x0; o1 = x1;
}

__global__ void keys_k(uint32_t* __restrict__ kb) {
  int i = threadIdx.x;
  if (i < STEPS) {
    uint32_t a, b;
    tf2x32(0u, 42u, 0u, (uint32_t)i, a, b);
    kb[2 * i] = a;
    kb[2 * i + 1] = b;
  }
}

__global__ void wt_k(const float* __restrict__ w2, float* __restrict__ wT) {
  int i = blockIdx.x * blockDim.x + threadIdx.x;
  if (i >= 25000) return;
  int oc = i / 500, q = i % 500;
  wT[q * 50 + oc] = w2[i];
}

// ---------------------------------------------------------------------------
// PERSISTENT per-sample kernel v3: one 512-thread block = one sample, all
// 100 steps. m1/m1s membranes in registers (thread-private, oc-half split);
// m2/m2s membranes in LDS (no spill); weights forced scalar via
// readfirstlane; sp2 spikes packed to a 77-dword bitmask in LDS and stored
// COALESCED at [b][s][77]. Summation chains verbatim R8 -> bitwise identical.
// ---------------------------------------------------------------------------
__global__ __launch_bounds__(512, 4) void step_all_k(
    const float* __restrict__ x, const float* __restrict__ w1,
    const float* __restrict__ wT, const uint32_t* __restrict__ kb,
    uint32_t* __restrict__ sp2g) {
  __shared__ float   xh_l[784];         // |x|/2
  __shared__ int8_t  xs_l[784];         // sign(x)
  __shared__ int8_t  pois_l[784];
  __shared__ int8_t  sp1_l[20 * 196];
  __shared__ int8_t  s2_l[50 * 196];
  __shared__ float   m2_l[50 * 196];    // conv2 membranes (39.2 KB)
  __shared__ float   m2s_l[2450];       // pool2 membranes (9.8 KB)
  __shared__ uint8_t sp2b_l[2464];      // pool2 spike bytes

  const int b  = blockIdx.x;
  const int t  = threadIdx.x;
  const int lq = t & 255;                                  // pixel/quad
  const int ohu = __builtin_amdgcn_readfirstlane(t >> 8);  // oc-half (scalar)
  const bool act = lq < 196;
  const int qy = lq / 14, qx = lq % 14;

  // preload per-sample input transform; zero LDS membranes
  for (int p = t; p < 784; p += 512) {
    float xv = x[b * 784 + p];
    xh_l[p] = fabsf(xv) * 0.5f;
    xs_l[p] = (xv > 0.f) ? (int8_t)1 : ((xv < 0.f) ? (int8_t)-1 : (int8_t)0);
  }
  for (int i = t; i < 50 * 196; i += 512) m2_l[i] = 0.f;
  for (int i = t; i < 2450; i += 512) m2s_l[i] = 0.f;

  // register membranes: conv1 (4 quad-px x 10 oc of this half) + pool1 (10)
  float m1r[4][10], m1sr[10];
#pragma unroll
  for (int i = 0; i < 10; ++i) {
    m1sr[i] = 0.f;
#pragma unroll
    for (int tt = 0; tt < 4; ++tt) m1r[tt][i] = 0.f;
  }
  __syncthreads();

  for (int s = 0; s < STEPS; ++s) {
    // ---- P0: poisson spikes ----
    {
      uint32_t k0 = kb[2 * s], k1 = kb[2 * s + 1];
      for (int p = t; p < 784; p += 512) {
        uint32_t o0, o1;
        tf2x32(k0, k1, 0u, (uint32_t)(b * 784 + p), o0, o1);
        float r = __uint_as_float(((o0 ^ o1) >> 9) | 0x3F800000u) - 1.0f;
        pois_l[p] = (xh_l[p] > r) ? xs_l[p] : (int8_t)0;
      }
    }
    __syncthreads();

    // ---- P1: conv1 (10 oc of this half) + fire + pool1 + fire ----
    if (act) {
      float acc[4][10];
#pragma unroll
      for (int tt = 0; tt < 4; ++tt)
#pragma unroll
        for (int i = 0; i < 10; ++i) acc[tt][i] = 0.f;
#pragma unroll
      for (int tt = 0; tt < 4; ++tt) {
        int y = 2 * qy + (tt >> 1);
        int xx = 2 * qx + (tt & 1);
#pragma unroll
        for (int ky = 0; ky < 5; ++ky) {
          int iy = y + ky - 2;
          if (iy < 0 || iy >= 28) continue;
#pragma unroll
          for (int kx = 0; kx < 5; ++kx) {
            int ix = xx + kx - 2;
            if (ix < 0 || ix >= 28) continue;
            float v = (float)pois_l[iy * 28 + ix];
#pragma unroll
            for (int i = 0; i < 10; ++i)
              acc[tt][i] += w1[(ohu * 10 + i) * 25 + ky * 5 + kx] * v;
          }
        }
      }
#pragma unroll
      for (int i = 0; i < 10; ++i) {
        float s4[4];
#pragma unroll
        for (int tt = 0; tt < 4; ++tt) {
          float m = m1r[tt][i] + acc[tt][i];
          float sp = 0.f;
          if (m > 1.0f) { sp = 1.f; m = 0.f; }
          m1r[tt][i] = m;
          s4[tt] = sp;
        }
        float a = 0.25f * (((s4[0] + s4[1]) + s4[2]) + s4[3]);
        float mm = m1sr[i] + a;
        int8_t spp = 0;
        if (mm > 0.75f) { spp = 1; mm = 0.f; }
        m1sr[i] = mm;
        sp1_l[(ohu * 10 + i) * 196 + lq] = spp;
      }
    }
    __syncthreads();

    // ---- P2: conv2 (25 oc of this half) + fire, membranes in LDS ----
    if (act) {
      float acc[25];
#pragma unroll
      for (int i = 0; i < 25; ++i) acc[i] = 0.f;
      for (int ic = 0; ic < 20; ++ic) {
#pragma unroll
        for (int ky = 0; ky < 5; ++ky) {
          int iy = qy + ky - 2;
          if (iy < 0 || iy >= 14) continue;
#pragma unroll
          for (int kx = 0; kx < 5; ++kx) {
            int ix = qx + kx - 2;
            if (ix < 0 || ix >= 14) continue;
            float v = (float)sp1_l[ic * 196 + iy * 14 + ix];
            const float* wrow = wT + (ic * 25 + ky * 5 + kx) * 50 + ohu * 25;
#pragma unroll
            for (int i = 0; i < 25; ++i) acc[i] += wrow[i] * v;
          }
        }
      }
#pragma unroll
      for (int i = 0; i < 25; ++i) {
        int li = (ohu * 25 + i) * 196 + lq;
        float m = m2_l[li] + acc[i];
        int8_t sp = 0;
        if (m > 1.0f) { sp = 1; m = 0.f; }
        m2_l[li] = m;
        s2_l[li] = sp;
      }
    }
    __syncthreads();

    // ---- P3: pool2 + fire -> spike bytes in LDS ----
    for (int e = t; e < 2450; e += 512) {
      int oc = e / 49, qq = e % 49;
      int yo = qq / 7, xo = qq % 7;
      int ib = oc * 196 + 2 * yo * 14 + 2 * xo;
      float a = 0.25f * ((((float)s2_l[ib] + (float)s2_l[ib + 1]) +
                          (float)s2_l[ib + 14]) + (float)s2_l[ib + 15]);
      float m = m2s_l[e] + a;
      uint8_t sp = 0;
      if (m > 0.75f) { sp = 1; m = 0.f; }
      m2s_l[e] = m;
      sp2b_l[e] = sp;
    }
    __syncthreads();

    // ---- P4: pack 77-dword bitmask, coalesced store [b][s][77] ----
    if (t < 77) {
      uint32_t pack = 0;
#pragma unroll
      for (int j = 0; j < 32; ++j) {
        int k = 32 * t + j;
        if (k < 2450) pack |= ((uint32_t)sp2b_l[k]) << j;
      }
      sp2g[b * 7700 + s * 77 + t] = pack;
    }
    __syncthreads();
  }
}

// ---------------------------------------------------------------------------
// fc0 over ALL steps. Thread = (n,b); mf0/Tf0 in registers across s.
// Bitmask unpack (w>>j)&1 -> exact 0.0/1.0; k ascending -> bit-identical.
// sp2 total 15.8 MB -> L2/L3-resident across the 200x n re-reads.
// ---------------------------------------------------------------------------
__global__ __launch_bounds__(256) void fc0f_k(
    const uint32_t* __restrict__ sp2g, const float* __restrict__ wf0,
    float* __restrict__ Tf0g) {
  int n = blockIdx.x >> 1;                        // block-uniform
  int b = ((blockIdx.x & 1) << 8) + threadIdx.x;  // 0..511
  const float* w0 = wf0 + n * 2450;               // scalar K$-resident row
  const uint32_t* sb = sp2g + b * 7700;
  float m = 0.f, T = 0.f;
  for (int s = 0; s < STEPS; ++s) {
    const uint32_t* base = sb + s * 77;
    float acc = 0.f;
    for (int d = 0; d < 76; d += 2) {             // unroll-2 for load MLP
      uint32_t wa = base[d];
      uint32_t wb = base[d + 1];
#pragma unroll
      for (int j = 0; j < 32; ++j)
        acc += w0[32 * d + j] * (float)((wa >> j) & 1u);
#pragma unroll
      for (int j = 0; j < 32; ++j)
        acc += w0[32 * (d + 1) + j] * (float)((wb >> j) & 1u);
    }
    {
      uint32_t wl = base[76];                     // k = 2432..2449
#pragma unroll
      for (int j = 0; j < 18; ++j)
        acc += w0[2432 + j] * (float)((wl >> j) & 1u);
    }
    m += acc;
    if (m > 1.0f) { T += 1.f; m = 0.f; }
  }
  Tf0g[n * 512 + b] = T;
}

// ---------------------------------------------------------------------------
// final: out[b][i] = (Tf0[.][b] . wf1[i][.]) / 1 / 100   (j ascending)
// ---------------------------------------------------------------------------
__global__ void fc1_k(const float* __restrict__ Tf0,
                      const float* __restrict__ wf1,
                      float* __restrict__ out) {
  int idx = blockIdx.x * blockDim.x + threadIdx.x;
  if (idx >= 5120) return;
  int b = idx / 10, i = idx % 10;
  float a = 0.f;
  for (int j = 0; j < 200; ++j) a += Tf0[j * 512 + b] * wf1[i * 200 + j];
  out[idx] = (a / 1.0f) / 100.0f;
}

// ---------------------------------------------------------------------------
extern "C" void kernel_launch(void* const* d_in, const int* in_sizes, int n_in,
                              void* d_out, int out_size, void* d_ws, size_t ws_size,
                              hipStream_t stream) {
  (void)in_sizes; (void)n_in; (void)out_size; (void)ws_size;
  const float* x   = (const float*)d_in[0];
  const float* w1  = (const float*)d_in[1];
  const float* w2  = (const float*)d_in[2];
  const float* wf0 = (const float*)d_in[3];
  const float* wf1 = (const float*)d_in[4];
  float* out = (float*)d_out;
  char* ws = (char*)d_ws;

  // workspace: Tf0 | wT | keys | sp2 bitmask  (~16.3 MB total)
  const size_t tf0_b = 200ull * 512 * 4;          //    409,600
  const size_t wt_b  = 25000ull * 4;              //    100,000
  const size_t key_b = 1024;
  float*    Tf0g = (float*)ws;
  float*    wT   = (float*)(ws + tf0_b);
  uint32_t* kb   = (uint32_t*)(ws + tf0_b + wt_b);
  uint32_t* sp2g = (uint32_t*)(ws + tf0_b + wt_b + key_b);  // 512*7700 dwords

  // no memset needed: every word read is written first
  keys_k<<<1, 128, 0, stream>>>(kb);
  wt_k<<<98, 256, 0, stream>>>(w2, wT);
  step_all_k<<<512, 512, 0, stream>>>(x, w1, wT, kb, sp2g);
  fc0f_k<<<400, 256, 0, stream>>>(sp2g, wf0, Tf0g);
  fc1_k<<<20, 256, 0, stream>>>(Tf0g, wf1, out);
}